// Round 1
// baseline (1502.296 us; speedup 1.0000x reference)
//
#include <hip/hip_runtime.h>
#include <hip/hip_bf16.h>
#include <math.h>

#define N_NODES 100000
#define N_EDGES 1600000
#define F_IN 100
#define H 64
#define C 18

// ----------------- CSR build -----------------

__global__ void hist_kernel(const int* __restrict__ tgt, int* __restrict__ cnt) {
    int i = blockIdx.x * blockDim.x + threadIdx.x;
    int stride = gridDim.x * blockDim.x;
    for (int e = i; e < N_EDGES; e += stride) atomicAdd(&cnt[tgt[e]], 1);
}

__global__ void scan1_kernel(const int* __restrict__ cnt, int* __restrict__ excl,
                             int* __restrict__ bsum) {
    __shared__ int tmp[256];
    int t = threadIdx.x;
    int i = blockIdx.x * 256 + t;
    int v = (i < N_NODES) ? cnt[i] : 0;
    tmp[t] = v;
    __syncthreads();
    for (int off = 1; off < 256; off <<= 1) {
        int xv = (t >= off) ? tmp[t - off] : 0;
        __syncthreads();
        tmp[t] += xv;
        __syncthreads();
    }
    if (i < N_NODES) excl[i] = tmp[t] - v;   // exclusive within block
    if (t == 255) bsum[blockIdx.x] = tmp[255];
}

__global__ void scan2_kernel(int* bsum, int nb) {
    if (blockIdx.x == 0 && threadIdx.x == 0) {
        int run = 0;
        for (int j = 0; j < nb; ++j) { int v = bsum[j]; bsum[j] = run; run += v; }
    }
}

__global__ void scan3_kernel(int* __restrict__ rp, const int* __restrict__ bsum) {
    int i = blockIdx.x * 256 + threadIdx.x;
    if (i < N_NODES) rp[i] += bsum[i >> 8];
    if (i == N_NODES) rp[N_NODES] = N_EDGES;
}

__global__ void dinv_kernel(const int* __restrict__ cnt, float* __restrict__ dinv) {
    int i = blockIdx.x * blockDim.x + threadIdx.x;
    if (i < N_NODES) {
        int c = cnt[i];
        dinv[i] = (c > 0) ? rsqrtf((float)c) : 0.0f;
    }
}

__global__ void scatter_kernel(const int* __restrict__ src, const int* __restrict__ tgt,
                               const int* __restrict__ rp, int* __restrict__ cursor,
                               const float* __restrict__ dinv,
                               int* __restrict__ ssrc, float* __restrict__ snorm) {
    int i = blockIdx.x * blockDim.x + threadIdx.x;
    int stride = gridDim.x * blockDim.x;
    for (int e = i; e < N_EDGES; e += stride) {
        int s = src[e], t = tgt[e];
        int pos = rp[t] + atomicAdd(&cursor[t], 1);
        ssrc[pos] = s;
        snorm[pos] = dinv[s] * dinv[t];
    }
}

// ----------------- dense mixes -----------------

// out[k,n,c] = sum_f x[n,f] * W[k,f,c]   (W: [2,F_IN,H], 51.2KB in LDS)
__global__ void dense_f100(const float* __restrict__ x, const float* __restrict__ W,
                           float* __restrict__ out) {
    __shared__ float Ws[2 * F_IN * H];
    int t = threadIdx.x;
    for (int i = t; i < 2 * F_IN * H; i += 256) Ws[i] = W[i];
    __syncthreads();
    int c = t & 63, r = t >> 6;
    for (int base = blockIdx.x * 4; base < N_NODES; base += gridDim.x * 4) {
        int n = base + r;
        if (n < N_NODES) {
            const float* xr = x + (size_t)n * F_IN;
            float a0 = 0.f, a1 = 0.f;
            #pragma unroll 4
            for (int f = 0; f < F_IN; ++f) {
                float xv = xr[f];
                a0 = fmaf(xv, Ws[f * H + c], a0);
                a1 = fmaf(xv, Ws[F_IN * H + f * H + c], a1);
            }
            out[(size_t)n * H + c] = a0;
            out[(size_t)(N_NODES + n) * H + c] = a1;
        }
    }
}

// out[k,n,g] = sum_f hin[k,n,f] * W[k,f,g]   (W: [2,64,64], 32KB LDS)
__global__ void dense_f64(const float* __restrict__ hin, const float* __restrict__ W,
                          float* __restrict__ out) {
    __shared__ float Ws[2 * H * H];
    int t = threadIdx.x;
    for (int i = t; i < 2 * H * H; i += 256) Ws[i] = W[i];
    __syncthreads();
    int c = t & 63, r = t >> 6;
    for (int base = blockIdx.x * 4; base < N_NODES; base += gridDim.x * 4) {
        int n = base + r;
        if (n < N_NODES) {
            const float* h0 = hin + (size_t)n * H;
            const float* h1 = hin + (size_t)(N_NODES + n) * H;
            float a0 = 0.f, a1 = 0.f;
            #pragma unroll 4
            for (int f = 0; f < H; ++f) {
                a0 = fmaf(h0[f], Ws[f * H + c], a0);
                a1 = fmaf(h1[f], Ws[H * H + f * H + c], a1);
            }
            out[(size_t)n * H + c] = a0;
            out[(size_t)(N_NODES + n) * H + c] = a1;
        }
    }
}

// h2[k,n,c] = sum_f y[n,f]*Wi[k,f,c];  root2[k,n,c] = sum_f y[n,f]*Wr[k,f,c]
__global__ void dense_y2(const float* __restrict__ y, const float* __restrict__ Wi,
                         const float* __restrict__ Wr,
                         float* __restrict__ h2, float* __restrict__ root2) {
    __shared__ float Wis[2 * H * C];
    __shared__ float Wrs[2 * H * C];
    int t = threadIdx.x;
    for (int i = t; i < 2 * H * C; i += 256) { Wis[i] = Wi[i]; Wrs[i] = Wr[i]; }
    __syncthreads();
    int p = blockIdx.x * 256 + t;
    if (p >= 2 * N_NODES) return;
    int k = (p >= N_NODES) ? 1 : 0;
    int n = p - k * N_NODES;
    const float* yr = y + (size_t)n * H;
    float ah[C], ar[C];
    #pragma unroll
    for (int c = 0; c < C; ++c) { ah[c] = 0.f; ar[c] = 0.f; }
    for (int f = 0; f < H; ++f) {
        float v = yr[f];
        const float* wi = &Wis[k * H * C + f * C];
        const float* wr = &Wrs[k * H * C + f * C];
        #pragma unroll
        for (int c = 0; c < C; ++c) {
            ah[c] = fmaf(v, wi[c], ah[c]);
            ar[c] = fmaf(v, wr[c], ar[c]);
        }
    }
    float* ho = h2 + ((size_t)k * N_NODES + n) * C;
    float* ro = root2 + ((size_t)k * N_NODES + n) * C;
    #pragma unroll
    for (int c = 0; c < C; ++c) { ho[c] = ah[c]; ro[c] = ar[c]; }
}

// out[k,n,c] = sum_j hin[k,n,j] * W[k,j,c]   (W: [2,18,18])
__global__ void dense_f18(const float* __restrict__ hin, const float* __restrict__ W,
                          float* __restrict__ out) {
    __shared__ float Ws[2 * C * C];
    int t = threadIdx.x;
    for (int i = t; i < 2 * C * C; i += 256) Ws[i] = W[i];
    __syncthreads();
    int p = blockIdx.x * 256 + t;
    if (p >= 2 * N_NODES) return;
    int k = (p >= N_NODES) ? 1 : 0;
    int n = p - k * N_NODES;
    const float* hr = hin + ((size_t)k * N_NODES + n) * C;
    float acc[C];
    #pragma unroll
    for (int c = 0; c < C; ++c) acc[c] = 0.f;
    #pragma unroll
    for (int j = 0; j < C; ++j) {
        float v = hr[j];
        const float* wr = &Ws[k * C * C + j * C];
        #pragma unroll
        for (int c = 0; c < C; ++c) acc[c] = fmaf(v, wr[c], acc[c]);
    }
    float* o = out + ((size_t)k * N_NODES + n) * C;
    #pragma unroll
    for (int c = 0; c < C; ++c) o[c] = acc[c];
}

// ----------------- propagation (gather over CSR) -----------------

// one wave per target node, lane = feature column; both stacks per pass.
// FINAL=0: out[k,n,c] = relu(agg + root + b)
// FINAL=1: out[n,c]   = 0.5*(relu0 + relu1)   (stack mean; outer relu is a no-op)
template <int FINAL>
__global__ void prop64_kernel(const float* __restrict__ h, const float* __restrict__ root,
                              const float* __restrict__ b,
                              const int* __restrict__ rp, const int* __restrict__ ssrc,
                              const float* __restrict__ snorm, float* __restrict__ out) {
    int wid = (blockIdx.x * blockDim.x + threadIdx.x) >> 6;
    int lane = threadIdx.x & 63;
    if (wid >= N_NODES) return;
    int e0 = rp[wid], e1 = rp[wid + 1];
    const float* h1 = h + (size_t)N_NODES * H;
    float a0 = 0.f, a1 = 0.f;
    for (int e = e0; e < e1; ++e) {
        int s = ssrc[e];
        float w = snorm[e];
        a0 = fmaf(w, h[(size_t)s * H + lane], a0);
        a1 = fmaf(w, h1[(size_t)s * H + lane], a1);
    }
    float o0 = fmaxf(a0 + root[(size_t)wid * H + lane] + b[lane], 0.f);
    float o1 = fmaxf(a1 + root[(size_t)(N_NODES + wid) * H + lane] + b[H + lane], 0.f);
    if (FINAL) {
        out[(size_t)wid * H + lane] = 0.5f * (o0 + o1);
    } else {
        out[(size_t)wid * H + lane] = o0;
        out[(size_t)(N_NODES + wid) * H + lane] = o1;
    }
}

// one wave per target node, lanes 0..17 = class columns, both stacks.
// FINAL=1 additionally fuses stack-mean + log_softmax and writes [N,18].
template <int FINAL>
__global__ void prop18_kernel(const float* __restrict__ h, const float* __restrict__ root,
                              const float* __restrict__ b,
                              const int* __restrict__ rp, const int* __restrict__ ssrc,
                              const float* __restrict__ snorm, float* __restrict__ out) {
    int wid = (blockIdx.x * blockDim.x + threadIdx.x) >> 6;
    int lane = threadIdx.x & 63;
    if (wid >= N_NODES) return;
    int e0 = rp[wid], e1 = rp[wid + 1];
    const float* h1 = h + (size_t)N_NODES * C;
    bool act = lane < C;
    float a0 = 0.f, a1 = 0.f;
    for (int e = e0; e < e1; ++e) {
        int s = ssrc[e];
        float w = snorm[e];
        if (act) {
            a0 = fmaf(w, h[(size_t)s * C + lane], a0);
            a1 = fmaf(w, h1[(size_t)s * C + lane], a1);
        }
    }
    float o0 = 0.f, o1 = 0.f;
    if (act) {
        o0 = fmaxf(a0 + root[(size_t)wid * C + lane] + b[lane], 0.f);
        o1 = fmaxf(a1 + root[(size_t)(N_NODES + wid) * C + lane] + b[C + lane], 0.f);
    }
    if (!FINAL) {
        if (act) {
            out[(size_t)wid * C + lane] = o0;
            out[(size_t)(N_NODES + wid) * C + lane] = o1;
        }
    } else {
        float m = act ? 0.5f * (o0 + o1) : -INFINITY;
        // max across lanes 0..31 (xor masks <32 stay within the 32-lane half)
        float mx = m;
        #pragma unroll
        for (int off = 16; off >= 1; off >>= 1) mx = fmaxf(mx, __shfl_xor(mx, off, 64));
        float ex = act ? __expf(m - mx) : 0.f;
        float sum = ex;
        #pragma unroll
        for (int off = 16; off >= 1; off >>= 1) sum += __shfl_xor(sum, off, 64);
        if (act) out[(size_t)wid * C + lane] = m - mx - logf(sum);
    }
}

// ----------------- launch -----------------

extern "C" void kernel_launch(void* const* d_in, const int* in_sizes, int n_in,
                              void* d_out, int out_size, void* d_ws, size_t ws_size,
                              hipStream_t stream) {
    const float* x        = (const float*)d_in[0];
    const int*   ei       = (const int*)d_in[1];
    const float* init_w1  = (const float*)d_in[2];
    const float* w1       = (const float*)d_in[3];
    const float* root_w1  = (const float*)d_in[4];
    const float* b1       = (const float*)d_in[5];
    const float* init_w2  = (const float*)d_in[6];
    const float* w2       = (const float*)d_in[7];
    const float* root_w2  = (const float*)d_in[8];
    const float* b2       = (const float*)d_in[9];
    const int* src = ei;
    const int* tgt = ei + N_EDGES;
    float* out = (float*)d_out;

    char* w = (char*)d_ws;
    size_t off = 0;
    auto alloc = [&](size_t bytes) -> char* {
        char* p = w + off;
        off += (bytes + 255) & ~(size_t)255;
        return p;
    };
    int*   cnt    = (int*)alloc((size_t)N_NODES * 4);
    int*   rp     = (int*)alloc((size_t)(N_NODES + 1) * 4);
    int*   cursor = (int*)alloc((size_t)N_NODES * 4);
    float* dinv   = (float*)alloc((size_t)N_NODES * 4);
    int*   bsum   = (int*)alloc(512 * 4);
    int*   ssrc   = (int*)alloc((size_t)N_EDGES * 4);
    float* snorm  = (float*)alloc((size_t)N_EDGES * 4);
    float* hA     = (float*)alloc((size_t)2 * N_NODES * H * 4);
    float* hB     = (float*)alloc((size_t)2 * N_NODES * H * 4);
    float* root1  = (float*)alloc((size_t)2 * N_NODES * H * 4);
    float* y      = (float*)alloc((size_t)N_NODES * H * 4);
    // layer-2 buffers reuse hA (needs 3 * 2*N*18 = 10.8M floats <= 12.8M)
    float* h2    = hA;
    float* h2o   = hA + (size_t)2 * N_NODES * C;
    float* root2 = hA + (size_t)4 * N_NODES * C;
    float* h3    = hB;

    hipMemsetAsync(cnt, 0, (size_t)N_NODES * 4, stream);
    hipMemsetAsync(cursor, 0, (size_t)N_NODES * 4, stream);

    int nb = (N_NODES + 255) / 256;  // 391
    hist_kernel<<<1024, 256, 0, stream>>>(tgt, cnt);
    scan1_kernel<<<nb, 256, 0, stream>>>(cnt, rp, bsum);
    scan2_kernel<<<1, 64, 0, stream>>>(bsum, nb);
    scan3_kernel<<<(N_NODES + 1 + 255) / 256, 256, 0, stream>>>(rp, bsum);
    dinv_kernel<<<(N_NODES + 255) / 256, 256, 0, stream>>>(cnt, dinv);
    scatter_kernel<<<1024, 256, 0, stream>>>(src, tgt, rp, cursor, dinv, ssrc, snorm);

    // ---- layer 1 (F_IN=100 -> H=64) ----
    dense_f100<<<2048, 256, 0, stream>>>(x, init_w1, hA);    // h(t=0)
    dense_f100<<<2048, 256, 0, stream>>>(x, root_w1, root1); // root (shared)
    int pgrid = (N_NODES * 64 + 255) / 256;  // 25000
    prop64_kernel<0><<<pgrid, 256, 0, stream>>>(hA, root1, b1, rp, ssrc, snorm, hB);
    dense_f64<<<2048, 256, 0, stream>>>(hB, w1, hA);         // h(t=1)
    prop64_kernel<1><<<pgrid, 256, 0, stream>>>(hA, root1, b1, rp, ssrc, snorm, y);

    // ---- layer 2 (H=64 -> C=18) ----
    int ygrid = (2 * N_NODES + 255) / 256;
    dense_y2<<<ygrid, 256, 0, stream>>>(y, init_w2, root_w2, h2, root2);
    prop18_kernel<0><<<pgrid, 256, 0, stream>>>(h2, root2, b2, rp, ssrc, snorm, h2o);
    dense_f18<<<ygrid, 256, 0, stream>>>(h2o, w2, h3);
    prop18_kernel<1><<<pgrid, 256, 0, stream>>>(h3, root2, b2, rp, ssrc, snorm, out);
}

// Round 2
// 1027.795 us; speedup vs baseline: 1.4617x; 1.4617x over previous
//
#include <hip/hip_runtime.h>
#include <hip/hip_bf16.h>
#include <math.h>

#define N_NODES 100000
#define N_EDGES 1600000
#define F_IN 100
#define H 64
#define C 18
#define NG 16   // nodes per wave in dense kernels

// ----------------- CSR build -----------------

__global__ void hist_kernel(const int* __restrict__ tgt, int* __restrict__ cnt) {
    int i = blockIdx.x * blockDim.x + threadIdx.x;
    int stride = gridDim.x * blockDim.x;
    for (int e = i; e < N_EDGES; e += stride) atomicAdd(&cnt[tgt[e]], 1);
}

__global__ void scan1_kernel(const int* __restrict__ cnt, int* __restrict__ excl,
                             int* __restrict__ bsum) {
    __shared__ int tmp[256];
    int t = threadIdx.x;
    int i = blockIdx.x * 256 + t;
    int v = (i < N_NODES) ? cnt[i] : 0;
    tmp[t] = v;
    __syncthreads();
    for (int off = 1; off < 256; off <<= 1) {
        int xv = (t >= off) ? tmp[t - off] : 0;
        __syncthreads();
        tmp[t] += xv;
        __syncthreads();
    }
    if (i < N_NODES) excl[i] = tmp[t] - v;   // exclusive within block
    if (t == 255) bsum[blockIdx.x] = tmp[255];
}

__global__ void scan2_kernel(int* bsum, int nb) {
    if (blockIdx.x == 0 && threadIdx.x == 0) {
        int run = 0;
        for (int j = 0; j < nb; ++j) { int v = bsum[j]; bsum[j] = run; run += v; }
    }
}

__global__ void scan3_kernel(int* __restrict__ rp, const int* __restrict__ bsum) {
    int i = blockIdx.x * 256 + threadIdx.x;
    if (i < N_NODES) rp[i] += bsum[i >> 8];
    if (i == N_NODES) rp[N_NODES] = N_EDGES;
}

__global__ void dinv_kernel(const int* __restrict__ cnt, float* __restrict__ dinv) {
    int i = blockIdx.x * blockDim.x + threadIdx.x;
    if (i < N_NODES) {
        int c = cnt[i];
        dinv[i] = (c > 0) ? rsqrtf((float)c) : 0.0f;
    }
}

__global__ void scatter_kernel(const int* __restrict__ src, const int* __restrict__ tgt,
                               const int* __restrict__ rp, int* __restrict__ cursor,
                               int* __restrict__ ssrc) {
    int i = blockIdx.x * blockDim.x + threadIdx.x;
    int stride = gridDim.x * blockDim.x;
    for (int e = i; e < N_EDGES; e += stride) {
        int s = src[e], t = tgt[e];
        int pos = rp[t] + atomicAdd(&cursor[t], 1);
        ssrc[pos] = s;
    }
}

// ----------------- dense mixes (register-blocked, no LDS) -----------------
// Pattern: wave owns NG=16 nodes; lane = output column. Activations are
// wave-uniform -> readfirstlane forces SGPR base -> s_load (SMEM path).
// Weights are coalesced per-lane vector loads, amortized over 16 nodes.
// dinv[n] is folded into outputs that feed propagation (h), NOT into root.

// h[k,n,c] = dinv[n] * sum_f x[n,f]*Wi[k,f,c];  root[k,n,c] = sum_f x[n,f]*Wr[k,f,c]
__global__ void __launch_bounds__(256) dense1_fused(
        const float* __restrict__ x, const float* __restrict__ Wi,
        const float* __restrict__ Wr, const float* __restrict__ dinv,
        float* __restrict__ h, float* __restrict__ root) {
    int lane = threadIdx.x & 63;
    int wid = __builtin_amdgcn_readfirstlane((int)((blockIdx.x * 256 + threadIdx.x) >> 6));
    int n0 = wid * NG;
    if (n0 >= N_NODES) return;
    float ai0[NG], ai1[NG], ar0[NG], ar1[NG];
    #pragma unroll
    for (int n = 0; n < NG; ++n) { ai0[n] = 0.f; ai1[n] = 0.f; ar0[n] = 0.f; ar1[n] = 0.f; }
    #pragma unroll 2
    for (int f = 0; f < F_IN; ++f) {
        float wi0 = Wi[f * H + lane];
        float wi1 = Wi[(F_IN + f) * H + lane];
        float wr0 = Wr[f * H + lane];
        float wr1 = Wr[(F_IN + f) * H + lane];
        #pragma unroll
        for (int n = 0; n < NG; ++n) {
            float xv = x[(n0 + n) * F_IN + f];   // uniform -> s_load
            ai0[n] = fmaf(xv, wi0, ai0[n]);
            ai1[n] = fmaf(xv, wi1, ai1[n]);
            ar0[n] = fmaf(xv, wr0, ar0[n]);
            ar1[n] = fmaf(xv, wr1, ar1[n]);
        }
    }
    #pragma unroll
    for (int n = 0; n < NG; ++n) {
        float dv = dinv[n0 + n];
        h[(size_t)(n0 + n) * H + lane]            = dv * ai0[n];
        h[(size_t)(N_NODES + n0 + n) * H + lane]  = dv * ai1[n];
        root[(size_t)(n0 + n) * H + lane]           = ar0[n];
        root[(size_t)(N_NODES + n0 + n) * H + lane] = ar1[n];
    }
}

// out[k,n,g] = dinv[n] * sum_f hin[k,n,f]*W[k,f,g]
__global__ void __launch_bounds__(256) dense_mid(
        const float* __restrict__ hin, const float* __restrict__ W,
        const float* __restrict__ dinv, float* __restrict__ out) {
    int lane = threadIdx.x & 63;
    int wid = __builtin_amdgcn_readfirstlane((int)((blockIdx.x * 256 + threadIdx.x) >> 6));
    int n0 = wid * NG;
    if (n0 >= N_NODES) return;
    float a0[NG], a1[NG];
    #pragma unroll
    for (int n = 0; n < NG; ++n) { a0[n] = 0.f; a1[n] = 0.f; }
    #pragma unroll 2
    for (int f = 0; f < H; ++f) {
        float w0 = W[f * H + lane];
        float w1v = W[(H + f) * H + lane];
        #pragma unroll
        for (int n = 0; n < NG; ++n) {
            float x0 = hin[(size_t)(n0 + n) * H + f];            // s_load
            float x1 = hin[(size_t)(N_NODES + n0 + n) * H + f];  // s_load
            a0[n] = fmaf(x0, w0, a0[n]);
            a1[n] = fmaf(x1, w1v, a1[n]);
        }
    }
    #pragma unroll
    for (int n = 0; n < NG; ++n) {
        float dv = dinv[n0 + n];
        out[(size_t)(n0 + n) * H + lane]           = dv * a0[n];
        out[(size_t)(N_NODES + n0 + n) * H + lane] = dv * a1[n];
    }
}

// h2[k,n,c] = dinv[n]*sum_f y[n,f]*Wi[k,f,c];  root2[k,n,c] = sum_f y[n,f]*Wr[k,f,c]
// lane -> (k = lane/18, c = lane%18), lanes 36..63 idle
__global__ void __launch_bounds__(256) dense_y2_kernel(
        const float* __restrict__ y, const float* __restrict__ Wi,
        const float* __restrict__ Wr, const float* __restrict__ dinv,
        float* __restrict__ h2, float* __restrict__ root2) {
    int lane = threadIdx.x & 63;
    int wid = __builtin_amdgcn_readfirstlane((int)((blockIdx.x * 256 + threadIdx.x) >> 6));
    int n0 = wid * NG;
    if (n0 >= N_NODES) return;
    bool act = lane < 36;
    int k = act ? (lane / 18) : 0;
    int c = act ? (lane % 18) : 0;
    float ah[NG], ar[NG];
    #pragma unroll
    for (int n = 0; n < NG; ++n) { ah[n] = 0.f; ar[n] = 0.f; }
    #pragma unroll 2
    for (int f = 0; f < H; ++f) {
        float wi = Wi[(k * H + f) * C + c];
        float wr = Wr[(k * H + f) * C + c];
        #pragma unroll
        for (int n = 0; n < NG; ++n) {
            float xv = y[(size_t)(n0 + n) * H + f];  // s_load
            ah[n] = fmaf(xv, wi, ah[n]);
            ar[n] = fmaf(xv, wr, ar[n]);
        }
    }
    if (act) {
        #pragma unroll
        for (int n = 0; n < NG; ++n) {
            float dv = dinv[n0 + n];
            h2[((size_t)k * N_NODES + n0 + n) * C + c]    = dv * ah[n];
            root2[((size_t)k * N_NODES + n0 + n) * C + c] = ar[n];
        }
    }
}

// out[k,n,c] = dinv[n] * sum_j hin[k,n,j]*W[k,j,c]   (lane = c, lanes 18..63 idle)
__global__ void __launch_bounds__(256) dense_last(
        const float* __restrict__ hin, const float* __restrict__ W,
        const float* __restrict__ dinv, float* __restrict__ out) {
    int lane = threadIdx.x & 63;
    int wid = __builtin_amdgcn_readfirstlane((int)((blockIdx.x * 256 + threadIdx.x) >> 6));
    int n0 = wid * NG;
    if (n0 >= N_NODES) return;
    bool act = lane < C;
    int c = act ? lane : 0;
    float a0[NG], a1[NG];
    #pragma unroll
    for (int n = 0; n < NG; ++n) { a0[n] = 0.f; a1[n] = 0.f; }
    #pragma unroll
    for (int j = 0; j < C; ++j) {
        float w0 = W[j * C + c];
        float w1v = W[(C + j) * C + c];
        #pragma unroll
        for (int n = 0; n < NG; ++n) {
            float x0 = hin[(size_t)(n0 + n) * C + j];            // s_load
            float x1 = hin[(size_t)(N_NODES + n0 + n) * C + j];  // s_load
            a0[n] = fmaf(x0, w0, a0[n]);
            a1[n] = fmaf(x1, w1v, a1[n]);
        }
    }
    if (act) {
        #pragma unroll
        for (int n = 0; n < NG; ++n) {
            float dv = dinv[n0 + n];
            out[(size_t)(n0 + n) * C + c]           = dv * a0[n];
            out[(size_t)(N_NODES + n0 + n) * C + c] = dv * a1[n];
        }
    }
}

// ----------------- propagation (gather over CSR) -----------------
// Input g is PRE-SCALED by dinv[src]; epilogue applies dinv[tgt].

template <int FINAL>
__global__ void prop64_kernel(const float* __restrict__ g, const float* __restrict__ root,
                              const float* __restrict__ b, const float* __restrict__ dinv,
                              const int* __restrict__ rp, const int* __restrict__ ssrc,
                              float* __restrict__ out) {
    int lane = threadIdx.x & 63;
    int wid = __builtin_amdgcn_readfirstlane((int)((blockIdx.x * 256 + threadIdx.x) >> 6));
    if (wid >= N_NODES) return;
    int e0 = rp[wid], e1 = rp[wid + 1];
    const float* g1 = g + (size_t)N_NODES * H;
    float a0 = 0.f, a1 = 0.f;
    for (int e = e0; e < e1; ++e) {
        int s = ssrc[e];                       // s_load (e uniform)
        a0 += g[(size_t)s * H + lane];
        a1 += g1[(size_t)s * H + lane];
    }
    float dv = dinv[wid];
    float o0 = fmaxf(fmaf(dv, a0, root[(size_t)wid * H + lane] + b[lane]), 0.f);
    float o1 = fmaxf(fmaf(dv, a1, root[(size_t)(N_NODES + wid) * H + lane] + b[H + lane]), 0.f);
    if (FINAL) {
        out[(size_t)wid * H + lane] = 0.5f * (o0 + o1);
    } else {
        out[(size_t)wid * H + lane] = o0;
        out[(size_t)(N_NODES + wid) * H + lane] = o1;
    }
}

template <int FINAL>
__global__ void prop18_kernel(const float* __restrict__ g, const float* __restrict__ root,
                              const float* __restrict__ b, const float* __restrict__ dinv,
                              const int* __restrict__ rp, const int* __restrict__ ssrc,
                              float* __restrict__ out) {
    int lane = threadIdx.x & 63;
    int wid = __builtin_amdgcn_readfirstlane((int)((blockIdx.x * 256 + threadIdx.x) >> 6));
    if (wid >= N_NODES) return;
    int e0 = rp[wid], e1 = rp[wid + 1];
    const float* g1 = g + (size_t)N_NODES * C;
    bool act = lane < C;
    float a0 = 0.f, a1 = 0.f;
    for (int e = e0; e < e1; ++e) {
        int s = ssrc[e];
        if (act) {
            a0 += g[(size_t)s * C + lane];
            a1 += g1[(size_t)s * C + lane];
        }
    }
    float dv = dinv[wid];
    float o0 = 0.f, o1 = 0.f;
    if (act) {
        o0 = fmaxf(fmaf(dv, a0, root[(size_t)wid * C + lane] + b[lane]), 0.f);
        o1 = fmaxf(fmaf(dv, a1, root[(size_t)(N_NODES + wid) * C + lane] + b[C + lane]), 0.f);
    }
    if (!FINAL) {
        if (act) {
            out[(size_t)wid * C + lane] = o0;
            out[(size_t)(N_NODES + wid) * C + lane] = o1;
        }
    } else {
        float m = act ? 0.5f * (o0 + o1) : -INFINITY;
        float mx = m;
        #pragma unroll
        for (int off = 16; off >= 1; off >>= 1) mx = fmaxf(mx, __shfl_xor(mx, off, 64));
        float ex = act ? __expf(m - mx) : 0.f;
        float sum = ex;
        #pragma unroll
        for (int off = 16; off >= 1; off >>= 1) sum += __shfl_xor(sum, off, 64);
        if (act) out[(size_t)wid * C + lane] = m - mx - logf(sum);
    }
}

// ----------------- launch -----------------

extern "C" void kernel_launch(void* const* d_in, const int* in_sizes, int n_in,
                              void* d_out, int out_size, void* d_ws, size_t ws_size,
                              hipStream_t stream) {
    const float* x        = (const float*)d_in[0];
    const int*   ei       = (const int*)d_in[1];
    const float* init_w1  = (const float*)d_in[2];
    const float* w1       = (const float*)d_in[3];
    const float* root_w1  = (const float*)d_in[4];
    const float* b1       = (const float*)d_in[5];
    const float* init_w2  = (const float*)d_in[6];
    const float* w2       = (const float*)d_in[7];
    const float* root_w2  = (const float*)d_in[8];
    const float* b2       = (const float*)d_in[9];
    const int* src = ei;
    const int* tgt = ei + N_EDGES;
    float* out = (float*)d_out;

    char* w = (char*)d_ws;
    size_t off = 0;
    auto alloc = [&](size_t bytes) -> char* {
        char* p = w + off;
        off += (bytes + 255) & ~(size_t)255;
        return p;
    };
    int*   cnt    = (int*)alloc((size_t)N_NODES * 4);
    int*   rp     = (int*)alloc((size_t)(N_NODES + 1) * 4);
    int*   cursor = (int*)alloc((size_t)N_NODES * 4);
    float* dinv   = (float*)alloc((size_t)N_NODES * 4);
    int*   bsum   = (int*)alloc(512 * 4);
    int*   ssrc   = (int*)alloc((size_t)N_EDGES * 4);
    float* hA     = (float*)alloc((size_t)2 * N_NODES * H * 4);
    float* hB     = (float*)alloc((size_t)2 * N_NODES * H * 4);
    float* root1  = (float*)alloc((size_t)2 * N_NODES * H * 4);
    float* y      = (float*)alloc((size_t)N_NODES * H * 4);
    // layer-2 buffers reuse hA (needs 3 * 2*N*18 = 10.8M floats <= 12.8M)
    float* h2    = hA;
    float* h2o   = hA + (size_t)2 * N_NODES * C;
    float* root2 = hA + (size_t)4 * N_NODES * C;
    float* h3    = hB;

    hipMemsetAsync(cnt, 0, (size_t)N_NODES * 4, stream);
    hipMemsetAsync(cursor, 0, (size_t)N_NODES * 4, stream);

    int nb = (N_NODES + 255) / 256;  // 391
    hist_kernel<<<1024, 256, 0, stream>>>(tgt, cnt);
    scan1_kernel<<<nb, 256, 0, stream>>>(cnt, rp, bsum);
    scan2_kernel<<<1, 64, 0, stream>>>(bsum, nb);
    scan3_kernel<<<(N_NODES + 1 + 255) / 256, 256, 0, stream>>>(rp, bsum);
    dinv_kernel<<<(N_NODES + 255) / 256, 256, 0, stream>>>(cnt, dinv);
    scatter_kernel<<<1024, 256, 0, stream>>>(src, tgt, rp, cursor, ssrc);

    int gblocks = (N_NODES / NG + 3) / 4;       // 1563 blocks of 4 waves
    int pgrid   = (N_NODES * 64 + 255) / 256;   // 25000 (wave per node)

    // ---- layer 1 (F_IN=100 -> H=64) ----
    dense1_fused<<<gblocks, 256, 0, stream>>>(x, init_w1, root_w1, dinv, hA, root1);
    prop64_kernel<0><<<pgrid, 256, 0, stream>>>(hA, root1, b1, dinv, rp, ssrc, hB);
    dense_mid<<<gblocks, 256, 0, stream>>>(hB, w1, dinv, hA);
    prop64_kernel<1><<<pgrid, 256, 0, stream>>>(hA, root1, b1, dinv, rp, ssrc, y);

    // ---- layer 2 (H=64 -> C=18) ----
    dense_y2_kernel<<<gblocks, 256, 0, stream>>>(y, init_w2, root_w2, dinv, h2, root2);
    prop18_kernel<0><<<pgrid, 256, 0, stream>>>(h2, root2, b2, dinv, rp, ssrc, h2o);
    dense_last<<<gblocks, 256, 0, stream>>>(h2o, w2, dinv, h3);
    prop18_kernel<1><<<pgrid, 256, 0, stream>>>(h3, root2, b2, dinv, rp, ssrc, out);
}

// Round 3
// 756.502 us; speedup vs baseline: 1.9858x; 1.3586x over previous
//
#include <hip/hip_runtime.h>
#include <hip/hip_bf16.h>
#include <math.h>

#define N_NODES 100000
#define N_EDGES 1600000
#define F_IN 100
#define H 64
#define C 18

// ----------------- CSR build -----------------

__global__ void hist_kernel(const int* __restrict__ tgt, int* __restrict__ cnt) {
    int i = blockIdx.x * blockDim.x + threadIdx.x;
    int stride = gridDim.x * blockDim.x;
    for (int e = i; e < N_EDGES; e += stride) atomicAdd(&cnt[tgt[e]], 1);
}

__global__ void scan1_kernel(const int* __restrict__ cnt, int* __restrict__ excl,
                             int* __restrict__ bsum) {
    __shared__ int tmp[256];
    int t = threadIdx.x;
    int i = blockIdx.x * 256 + t;
    int v = (i < N_NODES) ? cnt[i] : 0;
    tmp[t] = v;
    __syncthreads();
    for (int off = 1; off < 256; off <<= 1) {
        int xv = (t >= off) ? tmp[t - off] : 0;
        __syncthreads();
        tmp[t] += xv;
        __syncthreads();
    }
    if (i < N_NODES) excl[i] = tmp[t] - v;
    if (t == 255) bsum[blockIdx.x] = tmp[255];
}

__global__ void scan2_kernel(int* bsum, int nb) {
    if (blockIdx.x == 0 && threadIdx.x == 0) {
        int run = 0;
        for (int j = 0; j < nb; ++j) { int v = bsum[j]; bsum[j] = run; run += v; }
    }
}

__global__ void scan3_kernel(int* __restrict__ rp, const int* __restrict__ bsum) {
    int i = blockIdx.x * 256 + threadIdx.x;
    if (i < N_NODES) rp[i] += bsum[i >> 8];
    if (i == N_NODES) rp[N_NODES] = N_EDGES;
}

__global__ void dinv_kernel(const int* __restrict__ cnt, float* __restrict__ dinv) {
    int i = blockIdx.x * blockDim.x + threadIdx.x;
    if (i < N_NODES) {
        int c = cnt[i];
        dinv[i] = (c > 0) ? rsqrtf((float)c) : 0.0f;
    }
}

__global__ void scatter_kernel(const int* __restrict__ src, const int* __restrict__ tgt,
                               const int* __restrict__ rp, int* __restrict__ cursor,
                               int* __restrict__ ssrc) {
    int i = blockIdx.x * blockDim.x + threadIdx.x;
    int stride = gridDim.x * blockDim.x;
    for (int e = i; e < N_EDGES; e += stride) {
        int s = src[e], t = tgt[e];
        int pos = rp[t] + atomicAdd(&cursor[t], 1);
        ssrc[pos] = s;
    }
}

// ----------------- dense mixes (LDS-staged activations) -----------------
// Block = 256 threads = 4 waves; block stages 64 node-rows into LDS
// (coalesced), each wave computes 16 nodes, lane = output column.
// Activation reads are wave-uniform LDS broadcasts (conflict-free).
// dinv[n] is folded into outputs that feed propagation, NOT into root.
// Stack-interleaved layout for prop tables: [n][feat][2] (float2).

// h2o_[n*64+lane] = {dinv*sum x*Wi (k=0), dinv*sum x*Wi (k=1)}; root same w/o dinv
__global__ void __launch_bounds__(256) dense1_kernel(
        const float* __restrict__ x, const float* __restrict__ Wi,
        const float* __restrict__ Wr, const float* __restrict__ dinv,
        float2* __restrict__ h2o_, float2* __restrict__ root2o) {
    __shared__ float xs[64 * F_IN];
    int tid = threadIdx.x;
    int b0 = blockIdx.x * 64;
    int valid = min(64, N_NODES - b0);
    const float4* xg4 = (const float4*)(x + (size_t)b0 * F_IN);
    float4* xs4 = (float4*)xs;
    int cnt4 = valid * (F_IN / 4);
    for (int i = tid; i < cnt4; i += 256) xs4[i] = xg4[i];
    __syncthreads();
    int lane = tid & 63;
    int n0 = (tid >> 6) * 16;            // local node base (wave)
    if (b0 + n0 >= N_NODES) return;
    float ai0[16], ai1[16], ar0[16], ar1[16];
    #pragma unroll
    for (int n = 0; n < 16; ++n) { ai0[n]=0.f; ai1[n]=0.f; ar0[n]=0.f; ar1[n]=0.f; }
    const float2* xs2 = (const float2*)xs;
    for (int fp = 0; fp < F_IN / 2; ++fp) {
        int f = 2 * fp;
        float wi00 = Wi[f * H + lane],            wi01 = Wi[(f + 1) * H + lane];
        float wi10 = Wi[(F_IN + f) * H + lane],   wi11 = Wi[(F_IN + f + 1) * H + lane];
        float wr00 = Wr[f * H + lane],            wr01 = Wr[(f + 1) * H + lane];
        float wr10 = Wr[(F_IN + f) * H + lane],   wr11 = Wr[(F_IN + f + 1) * H + lane];
        #pragma unroll
        for (int n = 0; n < 16; ++n) {
            float2 xv = xs2[(n0 + n) * (F_IN / 2) + fp];
            ai0[n] = fmaf(xv.x, wi00, ai0[n]); ai0[n] = fmaf(xv.y, wi01, ai0[n]);
            ai1[n] = fmaf(xv.x, wi10, ai1[n]); ai1[n] = fmaf(xv.y, wi11, ai1[n]);
            ar0[n] = fmaf(xv.x, wr00, ar0[n]); ar0[n] = fmaf(xv.y, wr01, ar0[n]);
            ar1[n] = fmaf(xv.x, wr10, ar1[n]); ar1[n] = fmaf(xv.y, wr11, ar1[n]);
        }
    }
    #pragma unroll
    for (int n = 0; n < 16; ++n) {
        int gn = b0 + n0 + n;
        float dv = dinv[gn];
        h2o_[(size_t)gn * H + lane]   = make_float2(dv * ai0[n], dv * ai1[n]);
        root2o[(size_t)gn * H + lane] = make_float2(ar0[n], ar1[n]);
    }
}

// hin interleaved [n][64][2] -> out interleaved, per-stack W [2][64][64]
__global__ void __launch_bounds__(256) dense_mid_kernel(
        const float2* __restrict__ hin, const float* __restrict__ W,
        const float* __restrict__ dinv, float2* __restrict__ out) {
    __shared__ float2 hs[64 * H];   // 32 KB
    int tid = threadIdx.x;
    int b0 = blockIdx.x * 64;
    int valid = min(64, N_NODES - b0);
    const float4* src4 = (const float4*)(hin + (size_t)b0 * H);
    float4* dst4 = (float4*)hs;
    int cnt4 = valid * (H / 2);
    for (int i = tid; i < cnt4; i += 256) dst4[i] = src4[i];
    __syncthreads();
    int lane = tid & 63;
    int n0 = (tid >> 6) * 16;
    if (b0 + n0 >= N_NODES) return;
    float a0[16], a1[16];
    #pragma unroll
    for (int n = 0; n < 16; ++n) { a0[n] = 0.f; a1[n] = 0.f; }
    for (int f = 0; f < H; ++f) {
        float w0 = W[f * H + lane];
        float w1v = W[H * H + f * H + lane];
        #pragma unroll
        for (int n = 0; n < 16; ++n) {
            float2 xv = hs[(n0 + n) * H + f];
            a0[n] = fmaf(xv.x, w0, a0[n]);
            a1[n] = fmaf(xv.y, w1v, a1[n]);
        }
    }
    #pragma unroll
    for (int n = 0; n < 16; ++n) {
        int gn = b0 + n0 + n;
        float dv = dinv[gn];
        out[(size_t)gn * H + lane] = make_float2(dv * a0[n], dv * a1[n]);
    }
}

// y planar [n][64] -> h2 interleaved [n][18][2] (dinv-scaled), root2 interleaved
__global__ void __launch_bounds__(256) dense_y2_kernel(
        const float* __restrict__ y, const float* __restrict__ Wi,
        const float* __restrict__ Wr, const float* __restrict__ dinv,
        float2* __restrict__ h2, float2* __restrict__ root2) {
    __shared__ float ys[64 * H];    // 16 KB
    int tid = threadIdx.x;
    int b0 = blockIdx.x * 64;
    int valid = min(64, N_NODES - b0);
    const float4* src4 = (const float4*)(y + (size_t)b0 * H);
    float4* dst4 = (float4*)ys;
    int cnt4 = valid * (H / 4);
    for (int i = tid; i < cnt4; i += 256) dst4[i] = src4[i];
    __syncthreads();
    int lane = tid & 63;
    int n0 = (tid >> 6) * 16;
    if (b0 + n0 >= N_NODES) return;
    bool act = lane < C;
    int c = act ? lane : 0;
    float ah0[16], ah1[16], ar0[16], ar1[16];
    #pragma unroll
    for (int n = 0; n < 16; ++n) { ah0[n]=0.f; ah1[n]=0.f; ar0[n]=0.f; ar1[n]=0.f; }
    const float2* ys2 = (const float2*)ys;
    for (int fp = 0; fp < H / 2; ++fp) {
        int f = 2 * fp;
        float wi00 = Wi[f * C + c],                wi01 = Wi[(f + 1) * C + c];
        float wi10 = Wi[(H + f) * C + c],          wi11 = Wi[(H + f + 1) * C + c];
        float wr00 = Wr[f * C + c],                wr01 = Wr[(f + 1) * C + c];
        float wr10 = Wr[(H + f) * C + c],          wr11 = Wr[(H + f + 1) * C + c];
        #pragma unroll
        for (int n = 0; n < 16; ++n) {
            float2 xv = ys2[(n0 + n) * (H / 2) + fp];
            ah0[n] = fmaf(xv.x, wi00, ah0[n]); ah0[n] = fmaf(xv.y, wi01, ah0[n]);
            ah1[n] = fmaf(xv.x, wi10, ah1[n]); ah1[n] = fmaf(xv.y, wi11, ah1[n]);
            ar0[n] = fmaf(xv.x, wr00, ar0[n]); ar0[n] = fmaf(xv.y, wr01, ar0[n]);
            ar1[n] = fmaf(xv.x, wr10, ar1[n]); ar1[n] = fmaf(xv.y, wr11, ar1[n]);
        }
    }
    if (act) {
        #pragma unroll
        for (int n = 0; n < 16; ++n) {
            int gn = b0 + n0 + n;
            float dv = dinv[gn];
            h2[(size_t)gn * C + c]    = make_float2(dv * ah0[n], dv * ah1[n]);
            root2[(size_t)gn * C + c] = make_float2(ar0[n], ar1[n]);
        }
    }
}

// hin interleaved [n][18][2] -> out interleaved, W [2][18][18]
__global__ void __launch_bounds__(256) dense_last_kernel(
        const float2* __restrict__ hin, const float* __restrict__ W,
        const float* __restrict__ dinv, float2* __restrict__ out) {
    __shared__ float2 hs[64 * C];   // 9.2 KB
    int tid = threadIdx.x;
    int b0 = blockIdx.x * 64;
    int valid = min(64, N_NODES - b0);
    const float4* src4 = (const float4*)(hin + (size_t)b0 * C);
    float4* dst4 = (float4*)hs;
    int cnt4 = valid * C / 2;
    for (int i = tid; i < cnt4; i += 256) dst4[i] = src4[i];
    __syncthreads();
    int lane = tid & 63;
    int n0 = (tid >> 6) * 16;
    if (b0 + n0 >= N_NODES) return;
    bool act = lane < C;
    int c = act ? lane : 0;
    float a0[16], a1[16];
    #pragma unroll
    for (int n = 0; n < 16; ++n) { a0[n] = 0.f; a1[n] = 0.f; }
    #pragma unroll
    for (int j = 0; j < C; ++j) {
        float w0 = W[j * C + c];
        float w1v = W[C * C + j * C + c];
        #pragma unroll
        for (int n = 0; n < 16; ++n) {
            float2 xv = hs[(n0 + n) * C + j];
            a0[n] = fmaf(xv.x, w0, a0[n]);
            a1[n] = fmaf(xv.y, w1v, a1[n]);
        }
    }
    if (act) {
        #pragma unroll
        for (int n = 0; n < 16; ++n) {
            int gn = b0 + n0 + n;
            float dv = dinv[gn];
            out[(size_t)gn * C + c] = make_float2(dv * a0[n], dv * a1[n]);
        }
    }
}

// ----------------- propagation (gather over CSR, float2 stacks) -----------------
// g is PRE-SCALED by dinv[src]; epilogue applies dinv[tgt]. One wave/node.
// Unroll-4 software pipeline: 4 float2 gathers in flight per wave.

template <int FINAL>
__global__ void __launch_bounds__(256) prop64_kernel(
        const float2* __restrict__ g, const float2* __restrict__ root,
        const float* __restrict__ b, const float* __restrict__ dinv,
        const int* __restrict__ rp, const int* __restrict__ ssrc,
        float2* __restrict__ out2, float* __restrict__ outp) {
    int lane = threadIdx.x & 63;
    int wid = __builtin_amdgcn_readfirstlane((int)((blockIdx.x * 256 + threadIdx.x) >> 6));
    if (wid >= N_NODES) return;
    int e0 = rp[wid], e1 = rp[wid + 1];
    float a0 = 0.f, a1 = 0.f;
    int e = e0;
    for (; e + 4 <= e1; e += 4) {
        int s0 = ssrc[e], s1 = ssrc[e + 1], s2 = ssrc[e + 2], s3 = ssrc[e + 3];
        float2 v0 = g[(size_t)s0 * H + lane];
        float2 v1 = g[(size_t)s1 * H + lane];
        float2 v2 = g[(size_t)s2 * H + lane];
        float2 v3 = g[(size_t)s3 * H + lane];
        a0 += (v0.x + v1.x) + (v2.x + v3.x);
        a1 += (v0.y + v1.y) + (v2.y + v3.y);
    }
    for (; e < e1; ++e) {
        float2 v = g[(size_t)ssrc[e] * H + lane];
        a0 += v.x; a1 += v.y;
    }
    float dv = dinv[wid];
    float2 rt = root[(size_t)wid * H + lane];
    float o0 = fmaxf(fmaf(dv, a0, rt.x + b[lane]), 0.f);
    float o1 = fmaxf(fmaf(dv, a1, rt.y + b[H + lane]), 0.f);
    if (FINAL) {
        outp[(size_t)wid * H + lane] = 0.5f * (o0 + o1);
    } else {
        out2[(size_t)wid * H + lane] = make_float2(o0, o1);
    }
}

template <int FINAL>
__global__ void __launch_bounds__(256) prop18_kernel(
        const float2* __restrict__ g, const float2* __restrict__ root,
        const float* __restrict__ b, const float* __restrict__ dinv,
        const int* __restrict__ rp, const int* __restrict__ ssrc,
        float2* __restrict__ out2, float* __restrict__ outp) {
    int lane = threadIdx.x & 63;
    int wid = __builtin_amdgcn_readfirstlane((int)((blockIdx.x * 256 + threadIdx.x) >> 6));
    if (wid >= N_NODES) return;
    int e0 = rp[wid], e1 = rp[wid + 1];
    bool act = lane < C;
    int c = act ? lane : 0;
    float a0 = 0.f, a1 = 0.f;
    int e = e0;
    for (; e + 4 <= e1; e += 4) {
        int s0 = ssrc[e], s1 = ssrc[e + 1], s2 = ssrc[e + 2], s3 = ssrc[e + 3];
        float2 v0 = g[(size_t)s0 * C + c];
        float2 v1 = g[(size_t)s1 * C + c];
        float2 v2 = g[(size_t)s2 * C + c];
        float2 v3 = g[(size_t)s3 * C + c];
        if (act) {
            a0 += (v0.x + v1.x) + (v2.x + v3.x);
            a1 += (v0.y + v1.y) + (v2.y + v3.y);
        }
    }
    for (; e < e1; ++e) {
        float2 v = g[(size_t)ssrc[e] * C + c];
        if (act) { a0 += v.x; a1 += v.y; }
    }
    float dv = dinv[wid];
    float o0 = 0.f, o1 = 0.f;
    if (act) {
        float2 rt = root[(size_t)wid * C + c];
        o0 = fmaxf(fmaf(dv, a0, rt.x + b[c]), 0.f);
        o1 = fmaxf(fmaf(dv, a1, rt.y + b[C + c]), 0.f);
    }
    if (!FINAL) {
        if (act) out2[(size_t)wid * C + c] = make_float2(o0, o1);
    } else {
        float m = act ? 0.5f * (o0 + o1) : -INFINITY;
        float mx = m;
        #pragma unroll
        for (int off = 16; off >= 1; off >>= 1) mx = fmaxf(mx, __shfl_xor(mx, off, 64));
        float ex = act ? __expf(m - mx) : 0.f;
        float sum = ex;
        #pragma unroll
        for (int off = 16; off >= 1; off >>= 1) sum += __shfl_xor(sum, off, 64);
        if (act) outp[(size_t)wid * C + c] = m - mx - logf(sum);
    }
}

// ----------------- launch -----------------

extern "C" void kernel_launch(void* const* d_in, const int* in_sizes, int n_in,
                              void* d_out, int out_size, void* d_ws, size_t ws_size,
                              hipStream_t stream) {
    const float* x        = (const float*)d_in[0];
    const int*   ei       = (const int*)d_in[1];
    const float* init_w1  = (const float*)d_in[2];
    const float* w1       = (const float*)d_in[3];
    const float* root_w1  = (const float*)d_in[4];
    const float* b1       = (const float*)d_in[5];
    const float* init_w2  = (const float*)d_in[6];
    const float* w2       = (const float*)d_in[7];
    const float* root_w2  = (const float*)d_in[8];
    const float* b2       = (const float*)d_in[9];
    const int* src = ei;
    const int* tgt = ei + N_EDGES;
    float* out = (float*)d_out;

    char* w = (char*)d_ws;
    size_t off = 0;
    auto alloc = [&](size_t bytes) -> char* {
        char* p = w + off;
        off += (bytes + 255) & ~(size_t)255;
        return p;
    };
    int*    cnt    = (int*)alloc((size_t)N_NODES * 4);
    int*    rp     = (int*)alloc((size_t)(N_NODES + 1) * 4);
    int*    cursor = (int*)alloc((size_t)N_NODES * 4);
    float*  dinv   = (float*)alloc((size_t)N_NODES * 4);
    int*    bsum   = (int*)alloc(512 * 4);
    int*    ssrc   = (int*)alloc((size_t)N_EDGES * 4);
    float2* hA2    = (float2*)alloc((size_t)N_NODES * H * 8);   // 51.2 MB
    float2* hB2    = (float2*)alloc((size_t)N_NODES * H * 8);   // 51.2 MB
    float2* root12 = (float2*)alloc((size_t)N_NODES * H * 8);   // 51.2 MB
    float*  y      = (float*)alloc((size_t)N_NODES * H * 4);    // 25.6 MB
    // layer-2 interleaved buffers reuse hA2/hB2 (each needs N*18 float2 = 14.4MB)
    float2* h2i    = hA2;
    float2* h2oi   = hA2 + (size_t)N_NODES * C;
    float2* root2i = hA2 + (size_t)2 * N_NODES * C;
    float2* h3i    = hB2;

    hipMemsetAsync(cnt, 0, (size_t)N_NODES * 4, stream);
    hipMemsetAsync(cursor, 0, (size_t)N_NODES * 4, stream);

    int nb = (N_NODES + 255) / 256;  // 391
    hist_kernel<<<1024, 256, 0, stream>>>(tgt, cnt);
    scan1_kernel<<<nb, 256, 0, stream>>>(cnt, rp, bsum);
    scan2_kernel<<<1, 64, 0, stream>>>(bsum, nb);
    scan3_kernel<<<(N_NODES + 1 + 255) / 256, 256, 0, stream>>>(rp, bsum);
    dinv_kernel<<<(N_NODES + 255) / 256, 256, 0, stream>>>(cnt, dinv);
    scatter_kernel<<<1024, 256, 0, stream>>>(src, tgt, rp, cursor, ssrc);

    int gblocks = (N_NODES + 63) / 64;          // 1563 (64 nodes per block)
    int pgrid   = (N_NODES + 3) / 4;            // 25000 (wave per node)

    // ---- layer 1 (F_IN=100 -> H=64) ----
    dense1_kernel<<<gblocks, 256, 0, stream>>>(x, init_w1, root_w1, dinv, hA2, root12);
    prop64_kernel<0><<<pgrid, 256, 0, stream>>>(hA2, root12, b1, dinv, rp, ssrc, hB2, nullptr);
    dense_mid_kernel<<<gblocks, 256, 0, stream>>>(hB2, w1, dinv, hA2);
    prop64_kernel<1><<<pgrid, 256, 0, stream>>>(hA2, root12, b1, dinv, rp, ssrc, nullptr, y);

    // ---- layer 2 (H=64 -> C=18) ----
    dense_y2_kernel<<<gblocks, 256, 0, stream>>>(y, init_w2, root_w2, dinv, h2i, root2i);
    prop18_kernel<0><<<pgrid, 256, 0, stream>>>(h2i, root2i, b2, dinv, rp, ssrc, h2oi, nullptr);
    dense_last_kernel<<<gblocks, 256, 0, stream>>>(h2oi, w2, dinv, h3i);
    prop18_kernel<1><<<pgrid, 256, 0, stream>>>(h3i, root2i, b2, dinv, rp, ssrc, nullptr, out);
}